// Round 3
// baseline (11524.155 us; speedup 1.0000x reference)
//
#include <hip/hip_runtime.h>
#include <math.h>

#define N 4096
#define STEPS 16384
#define CHUNK 16
#define NCHUNK (STEPS / CHUNK)
#define MBLK 1024
#define SST 20   // padded row stride (floats) for ST / X1T (16B-aligned, bank-spread)

// Workgroup barrier that does NOT drain vmcnt: lets prefetch loads stay
// outstanding across the barrier (only LDS ordering is needed between phases).
__device__ __forceinline__ void lgkm_barrier() {
  asm volatile("s_waitcnt lgkmcnt(0)\n\ts_barrier" ::: "memory");
}

// ---- thresholds: thr[t] = atanh(2*u[t]-1) in double (r computed in fp32 like ref) ----
__global__ __launch_bounds__(256) void thr_kernel(const float* __restrict__ u,
                                                  double* __restrict__ thr) {
  int t = blockIdx.x * 256 + threadIdx.x;
  if (t < STEPS) {
    float r = 2.0f * u[t] - 1.0f;          // exact same fp32 rounding as reference
    double rd = (double)r;
    thr[t] = 0.5 * log((1.0 + rd) / (1.0 - rd));   // r=-1 -> -inf (tie->+1 matches ref)
  }
}

// ---- initial field: I0[row] = sum_k J[row,k]*m0[k] + h[row], fp64 accumulate ----
__global__ __launch_bounds__(256) void init_field_kernel(const float* __restrict__ J,
                                                         const float* __restrict__ h,
                                                         const float* __restrict__ m0,
                                                         double* __restrict__ I) {
  __shared__ double red[256];
  int row = blockIdx.x;
  const float4* Jr = (const float4*)(J + (size_t)row * N);
  const float4* mv = (const float4*)m0;
  double acc = 0.0;
  for (int q = threadIdx.x; q < N / 4; q += 256) {
    float4 a = Jr[q];
    float4 b = mv[q];
    acc += (double)(a.x * b.x) + (double)(a.y * b.y) +
           (double)(a.z * b.z) + (double)(a.w * b.w);
  }
  red[threadIdx.x] = acc;
  __syncthreads();
  for (int s = 128; s > 0; s >>= 1) {
    if (threadIdx.x < s) red[threadIdx.x] += red[threadIdx.x + s];
    __syncthreads();
  }
  if (threadIdx.x == 0) I[row] = red[0] + (double)h[row];
}

// ---- pipelined flip-driven Glauber chain: 1 workgroup, 1024 threads ----
// segR: wave0 resolves chunk c (field state = chunks <= c-2, + lag-1 X-matrix
//       correction for chunk c-1's deltas). Flip-driven: rounds = flips+1.
// segP: all other waves apply chunk c-1 (row loads were issued last segP ->
//       a full segR of latency hiding), then issue row loads for chunk c.
//       wave0 stores its prefetched S/X matrices (1.5 chunks of gather hiding).
// Barriers are lgkm-only so vector loads survive them.
__global__ __launch_bounds__(MBLK) void pbit_kernel(const float* __restrict__ J,
                                                    const float* __restrict__ m0,
                                                    const int* __restrict__ idx,
                                                    const double* __restrict__ thr,
                                                    const double* __restrict__ I0,
                                                    float* __restrict__ out) {
  __shared__ __align__(16) double field_lds[N];            // 32 KB master field
  __shared__ __align__(16) float m_lds[N];                 // 16 KB spins
  __shared__ __align__(16) float ST_lds[2][CHUNK * SST];   // S^T (in-chunk couplings)
  __shared__ __align__(16) float X1T_lds[2][CHUNK * SST];  // lag-1 cross couplings
  __shared__ __align__(16) int   pubi_lds[2][CHUNK];       // rows (0 if no flip)
  __shared__ __align__(16) float pubd_lds[2][CHUNK];       // deltas {-2,0,+2}
  __shared__ int pubab_lds[2];                             // any-flip flag

  const int tid = threadIdx.x;
  const bool isW0 = (tid < 64);

  // ---- field ownership: wave0 excluded (resolver). threads 64..1023 own
  // main cols cb..cb+3 (256..4095); threads 64..319 own extra col tid-64 (0..255).
  double i0 = 0, i1 = 0, i2d = 0, i3d = 0, ixd = 0;
  int cb = 0;
  if (!isW0) {
    cb = 256 + 4 * (tid - 64);
    const double* ip = I0 + cb;
    i0 = ip[0]; i1 = ip[1]; i2d = ip[2]; i3d = ip[3];
    *(double2*)(field_lds + cb + 0) = make_double2(i0, i1);
    *(double2*)(field_lds + cb + 2) = make_double2(i2d, i3d);
    if (tid < 320) { ixd = I0[tid - 64]; field_lds[tid - 64] = ixd; }
  }
  ((float4*)m_lds)[tid] = ((const float4*)m0)[tid];
  __syncthreads();

  const int t16 = tid & 15;
  const int gt = tid >> 2;        // 0..15 (wave0): gather row slot
  const int gq = (tid & 3) * 4;   // gather col group

  // wave0 pipeline registers
  int mi = 0, ni = 0, s2i = 0, s3i = 0;
  double mt = 0, nt = 0, s2t = 0, s3t = 0;
  int growA = 0, growB = 0, grow3 = 0;
  int gc0 = 0, gc1 = 0, gc2 = 0, gc3 = 0;
  int g3c0 = 0, g3c1 = 0, g3c2 = 0, g3c3 = 0;
  float pS0 = 0, pS1 = 0, pS2 = 0, pS3 = 0, pX0 = 0, pX1 = 0, pX2 = 0, pX3 = 0;
  float cS0 = 0, cS1 = 0, cS2 = 0, cS3 = 0, cX0 = 0, cX1 = 0, cX2 = 0, cX3 = 0;
  float mym = 0.f;
  bool lastocc = true;

  if (isW0) {
    // idx/thr stages for chunks 0,1,2 (t16 layout)
    mi  = idx[t16];      mt  = thr[t16];
    ni  = idx[16 + t16]; nt  = thr[16 + t16];
    s2i = idx[32 + t16]; s2t = thr[32 + t16];
    // gather layouts
    int g0row = idx[gt];
    int g0c0 = idx[gq], g0c1 = idx[gq + 1], g0c2 = idx[gq + 2], g0c3 = idx[gq + 3];
    int g1row = idx[16 + gt];
    int g1c0 = idx[16 + gq], g1c1 = idx[16 + gq + 1];
    int g1c2 = idx[16 + gq + 2], g1c3 = idx[16 + gq + 3];
    growB = idx[32 + gt];
    gc0 = idx[32 + gq]; gc1 = idx[32 + gq + 1];
    gc2 = idx[32 + gq + 2]; gc3 = idx[32 + gq + 3];
    growA = g1row;
    // sync gather+store S(0), X1(0)[dummy, deltas are 0] -> buf 0
    {
      const float* r0 = J + (size_t)g0row * N;
      float a = r0[g0c0], b = r0[g0c1], cc = r0[g0c2], d = r0[g0c3];
      ST_lds[0][(gq + 0) * SST + gt] = a;
      ST_lds[0][(gq + 1) * SST + gt] = b;
      ST_lds[0][(gq + 2) * SST + gt] = cc;
      ST_lds[0][(gq + 3) * SST + gt] = d;
      X1T_lds[0][(gq + 0) * SST + gt] = a;   // finite placeholder (multiplied by 0)
      X1T_lds[0][(gq + 1) * SST + gt] = b;
      X1T_lds[0][(gq + 2) * SST + gt] = cc;
      X1T_lds[0][(gq + 3) * SST + gt] = d;
    }
    // sync gather S(1), X1(1) into prevGather regs (stored to buf1 in segP(0))
    {
      const float* r1 = J + (size_t)g1row * N;   // S(1): rows idx1, cols idx1
      pS0 = r1[g1c0]; pS1 = r1[g1c1]; pS2 = r1[g1c2]; pS3 = r1[g1c3];
      const float* r0 = J + (size_t)g0row * N;   // X1(1): rows idx0, cols idx1
      pX0 = r0[g1c0]; pX1 = r0[g1c1]; pX2 = r0[g1c2]; pX3 = r0[g1c3];
    }
    if (tid < 16) pubd_lds[1][t16] = 0.0f;       // "chunk -1" deltas = 0
    if (tid == 0) { pubab_lds[0] = 0; pubab_lds[1] = 0; }
    mym = m_lds[mi];
    lastocc = true;
#pragma unroll
    for (int tt = 1; tt < 16; ++tt) {
      int ib = __builtin_amdgcn_readlane(mi, tt);
      if ((tt > t16) && (ib == mi)) lastocc = false;
    }
  }

  // P2 persistent state
  float4 rv[16];
  float rvx[16];
  int abprev = 0;

  for (int c = 0; c < NCHUNK; ++c) {
    const int cbuf = c & 1;

    // ================= segR : wave0 resolves chunk c =================
    if (isW0) {
      // issue S/X gathers for c+2 (consumed ~1.5 chunks from now)
      const float* Sp = J + (size_t)growB * N;
      cS0 = Sp[gc0]; cS1 = Sp[gc1]; cS2 = Sp[gc2]; cS3 = Sp[gc3];
      const float* Xp = J + (size_t)growA * N;
      cX0 = Xp[gc0]; cX1 = Xp[gc1]; cX2 = Xp[gc2]; cX3 = Xp[gc3];
      // issue idx/thr loads for c+3
      int b3 = c * CHUNK + 48;
      if (b3 >= STEPS) b3 = 0;
      s3i = idx[b3 + t16]; s3t = thr[b3 + t16];
      grow3 = idx[b3 + gt];
      g3c0 = idx[b3 + gq];     g3c1 = idx[b3 + gq + 1];
      g3c2 = idx[b3 + gq + 2]; g3c3 = idx[b3 + gq + 3];

      // base (field = chunks <= c-2) + lag-1 correction for chunk c-1
      double Ival = field_lds[mi];
      const float* x1r = &X1T_lds[cbuf][t16 * SST];
      float4 xa = *(const float4*)(x1r + 0);
      float4 xb = *(const float4*)(x1r + 4);
      float4 xc = *(const float4*)(x1r + 8);
      float4 xd = *(const float4*)(x1r + 12);
      const float* dp = pubd_lds[1 - cbuf];
      float4 da = *(const float4*)(dp + 0);
      float4 db = *(const float4*)(dp + 4);
      float4 dc = *(const float4*)(dp + 8);
      float4 dd = *(const float4*)(dp + 12);
      float corr = ((xa.x * da.x + xa.y * da.y) + (xa.z * da.z + xa.w * da.w))
                 + ((xb.x * db.x + xb.y * db.y) + (xb.z * db.z + xb.w * db.w))
                 + ((xc.x * dc.x + xc.y * dc.y) + (xc.z * dc.z + xc.w * dc.w))
                 + ((xd.x * dd.x + xd.y * dd.y) + (xd.z * dd.z + xd.w * dd.w));
      Ival += (double)corr;

      // flip-driven resolve: rounds = flips + 1
      float mcur = mym;
      float finals = 0.f, finald = 0.f;
      int conf = -1;
      bool locked = false;
      while (true) {
        float s = (Ival >= mt) ? 1.0f : -1.0f;   // I >= atanh(r) <=> tanh(I) >= r
        float dl = s - mcur;
        unsigned long long mask = __ballot(dl != 0.0f);
        mask &= 0xFFFFull;
        mask &= (~0ull) << (conf + 1);
        if (mask == 0) {
          if (!locked) { finals = s; finald = 0.0f; }
          break;
        }
        int f = (int)__builtin_ctzll(mask);      // wave-uniform
        if (!locked && t16 <= f) { finals = s; finald = dl; locked = true; }
        float dl_f = __int_as_float(__builtin_amdgcn_readlane(__float_as_int(dl), f));
        float s_f  = __int_as_float(__builtin_amdgcn_readlane(__float_as_int(s), f));
        int   i_f  = __builtin_amdgcn_readlane(mi, f);
        float xcol = ST_lds[cbuf][f * SST + t16];   // J[idx_t16][idx_f] (J symmetric)
        Ival += (double)(xcol * dl_f);              // exact product: dl in {-2,2}
        if (mi == i_f) mcur = s_f;                  // in-chunk duplicate index
        conf = f;
      }
      // publish decisions + m updates (last occurrence wins)
      if (tid < 16) {
        pubd_lds[cbuf][t16] = finald;
        pubi_lds[cbuf][t16] = (finald != 0.0f) ? mi : 0;
        if (lastocc) m_lds[mi] = finals;
      }
      if (tid == 0) pubab_lds[cbuf] = (conf >= 0) ? 1 : 0;
      // next-chunk m gather + lastocc (same wave => ordered after m writes)
      mym = m_lds[ni];
      lastocc = true;
#pragma unroll
      for (int tt = 1; tt < 16; ++tt) {
        int ib = __builtin_amdgcn_readlane(ni, tt);
        if ((tt > t16) && (ib == ni)) lastocc = false;
      }
    }
    lgkm_barrier();   // pub/m visible; wave0 base reads done before field writes

    // ================= segP : apply c-1, produce c =================
    if (!isW0) {
      if (abprev) {
        const float* dp = pubd_lds[1 - cbuf];   // deltas of chunk c-1
        float4 da = *(const float4*)(dp + 0);
        float4 db = *(const float4*)(dp + 4);
        float4 dc = *(const float4*)(dp + 8);
        float4 dd = *(const float4*)(dp + 12);
        float dv[16] = {da.x, da.y, da.z, da.w, db.x, db.y, db.z, db.w,
                        dc.x, dc.y, dc.z, dc.w, dd.x, dd.y, dd.z, dd.w};
        float a0 = 0.f, a1 = 0.f, a2 = 0.f, a3 = 0.f;
#pragma unroll
        for (int t = 0; t < 16; ++t) {
          a0 += rv[t].x * dv[t]; a1 += rv[t].y * dv[t];
          a2 += rv[t].z * dv[t]; a3 += rv[t].w * dv[t];
        }
        i0 += (double)a0; i1 += (double)a1; i2d += (double)a2; i3d += (double)a3;
        *(double2*)(field_lds + cb + 0) = make_double2(i0, i1);
        *(double2*)(field_lds + cb + 2) = make_double2(i2d, i3d);
        if (tid < 320) {
          float ax = 0.f;
#pragma unroll
          for (int t = 0; t < 16; ++t) ax += rvx[t] * dv[t];
          ixd += (double)ax;
          field_lds[tid - 64] = ixd;
        }
      }
      // produce chunk c: issue row loads (consumed next segP -> hidden across segR)
      int ab = pubab_lds[cbuf];
      abprev = ab;
      if (ab) {
        const int* pi = pubi_lds[cbuf];
        int4 ra = *(const int4*)(pi + 0);
        int4 rb = *(const int4*)(pi + 4);
        int4 rc = *(const int4*)(pi + 8);
        int4 rd = *(const int4*)(pi + 12);
        int rows[16] = {ra.x, ra.y, ra.z, ra.w, rb.x, rb.y, rb.z, rb.w,
                        rc.x, rc.y, rc.z, rc.w, rd.x, rd.y, rd.z, rd.w};
#pragma unroll
        for (int t = 0; t < 16; ++t) {
          const float* rp = J + (size_t)rows[t] * N;
          rv[t] = *(const float4*)(rp + cb);
          if (tid < 320) rvx[t] = rp[tid - 64];
        }
      }
    } else {
      // wave0: store prefetched S/X (for chunk c+1) into bufs[(c+1)&1]
      int nb = 1 - cbuf;
      ST_lds[nb][(gq + 0) * SST + gt] = pS0;
      ST_lds[nb][(gq + 1) * SST + gt] = pS1;
      ST_lds[nb][(gq + 2) * SST + gt] = pS2;
      ST_lds[nb][(gq + 3) * SST + gt] = pS3;
      X1T_lds[nb][(gq + 0) * SST + gt] = pX0;
      X1T_lds[nb][(gq + 1) * SST + gt] = pX1;
      X1T_lds[nb][(gq + 2) * SST + gt] = pX2;
      X1T_lds[nb][(gq + 3) * SST + gt] = pX3;
      // rotate gather + pipeline registers
      pS0 = cS0; pS1 = cS1; pS2 = cS2; pS3 = cS3;
      pX0 = cX0; pX1 = cX1; pX2 = cX2; pX3 = cX3;
      mi = ni; mt = nt; ni = s2i; nt = s2t; s2i = s3i; s2t = s3t;
      growA = growB; growB = grow3;
      gc0 = g3c0; gc1 = g3c1; gc2 = g3c2; gc3 = g3c3;
    }
    lgkm_barrier();
  }

  __syncthreads();
  ((float4*)out)[tid] = ((const float4*)m_lds)[tid];
}

extern "C" void kernel_launch(void* const* d_in, const int* in_sizes, int n_in,
                              void* d_out, int out_size, void* d_ws, size_t ws_size,
                              hipStream_t stream) {
  const float* J = (const float*)d_in[0];
  const float* h = (const float*)d_in[1];
  const float* m0 = (const float*)d_in[2];
  const int* idx = (const int*)d_in[3];
  const float* u = (const float*)d_in[4];
  float* out = (float*)d_out;

  double* thr = (double*)d_ws;                                    // 16384 doubles
  double* I0 = (double*)((char*)d_ws + STEPS * sizeof(double));   // 4096 doubles

  thr_kernel<<<dim3(STEPS / 256), dim3(256), 0, stream>>>(u, thr);
  init_field_kernel<<<dim3(N), dim3(256), 0, stream>>>(J, h, m0, I0);
  pbit_kernel<<<dim3(1), dim3(MBLK), 0, stream>>>(J, m0, idx, thr, I0, out);
}

// Round 4
// 2183.880 us; speedup vs baseline: 5.2769x; 5.2769x over previous
//
#include <hip/hip_runtime.h>
#include <math.h>

#define N 4096
#define STEPS 16384
#define CHUNK 16
#define NCHUNK (STEPS / CHUNK)
#define MBLK 1024
#define SST 20   // padded stride (floats) for ST: float4-aligned, 2-way-bank max (free)

// Workgroup barrier that does NOT drain vmcnt (LDS-only ordering between phases).
__device__ __forceinline__ void lgkm_barrier() {
  asm volatile("s_waitcnt lgkmcnt(0)\n\ts_barrier" ::: "memory");
}

// ---- prep: thr[t] = atanh(2u-1) in fp64; lastocc[t] = no later same-idx in chunk ----
__global__ __launch_bounds__(256) void pre_kernel(const float* __restrict__ u,
                                                  const int* __restrict__ idx,
                                                  double* __restrict__ thr,
                                                  int* __restrict__ lastocc) {
  int t = blockIdx.x * 256 + threadIdx.x;
  if (t < STEPS) {
    float r = 2.0f * u[t] - 1.0f;          // exact same fp32 rounding as reference
    double rd = (double)r;
    thr[t] = 0.5 * log((1.0 + rd) / (1.0 - rd));   // r=-1 -> -inf (tie->+1 matches ref)
    int cbase = t & ~(CHUNK - 1);
    int my = idx[t];
    int lo = 1;
    for (int tt = (t & (CHUNK - 1)) + 1; tt < CHUNK; ++tt)
      if (idx[cbase + tt] == my) { lo = 0; break; }
    lastocc[t] = lo;
  }
}

// ---- initial field: I0[row] = sum_k J[row,k]*m0[k] + h[row], fp64 accumulate ----
__global__ __launch_bounds__(256) void init_field_kernel(const float* __restrict__ J,
                                                         const float* __restrict__ h,
                                                         const float* __restrict__ m0,
                                                         double* __restrict__ I) {
  __shared__ double red[256];
  int row = blockIdx.x;
  const float4* Jr = (const float4*)(J + (size_t)row * N);
  const float4* mv = (const float4*)m0;
  double acc = 0.0;
  for (int q = threadIdx.x; q < N / 4; q += 256) {
    float4 a = Jr[q];
    float4 b = mv[q];
    acc += (double)(a.x * b.x) + (double)(a.y * b.y) +
           (double)(a.z * b.z) + (double)(a.w * b.w);
  }
  red[threadIdx.x] = acc;
  __syncthreads();
  for (int s = 128; s > 0; s >>= 1) {
    if (threadIdx.x < s) red[threadIdx.x] += red[threadIdx.x + s];
    __syncthreads();
  }
  if (threadIdx.x == 0) I[row] = red[0] + (double)h[row];
}

// ---- chunk-resolved Glauber chain: 1 workgroup, 1024 threads ----
// P1: wave0 resolves 16 steps flip-driven (rounds = flips+1) with the 16x16
//     coupling matrix register-resident; publishes a COMPACTED flip list.
// P2: all threads apply only the F flipped rows (uniform branches), fp64
//     register field + LDS write-through. Barriers are lgkm-only.
__global__ __launch_bounds__(MBLK) void pbit_kernel(const float* __restrict__ J,
                                                    const float* __restrict__ m0,
                                                    const int* __restrict__ idx,
                                                    const double* __restrict__ thr,
                                                    const int* __restrict__ lastocc,
                                                    const double* __restrict__ I0,
                                                    float* __restrict__ out) {
  __shared__ __align__(16) double field_lds[N];        // 32 KB master field
  __shared__ __align__(16) float m_lds[N];             // 16 KB spins
  __shared__ __align__(16) float ST_lds[CHUNK * SST];  // ST[c*SST+r] = J[idx[r]][idx[c]]
  __shared__ __align__(16) int   pubi_lds[CHUNK];      // compacted flip rows
  __shared__ __align__(16) float pubd_lds[CHUNK];      // compacted deltas (+/-2)
  __shared__ int pubF_lds;                             // flip count

  const int tid = threadIdx.x;

  // owned field elements 4*tid..4*tid+3: fp64 registers + LDS write-through
  double i0, i1, i2, i3;
  {
    const double* ip = I0 + 4 * tid;
    i0 = ip[0]; i1 = ip[1]; i2 = ip[2]; i3 = ip[3];
    *(double2*)(field_lds + 4 * tid + 0) = make_double2(i0, i1);
    *(double2*)(field_lds + 4 * tid + 2) = make_double2(i2, i3);
  }
  ((float4*)m_lds)[tid] = ((const float4*)m0)[tid];

  const int t16 = tid & 15;       // step slot within chunk
  const int gt = tid >> 2;        // gather row slot (wave0: 0..15)
  const int gq = (tid & 3) * 4;   // gather col group

  int mi = 0, ni = 0, mlo = 0, nlo = 0;
  double mt = 0.0, nt = 0.0;
  int grow = 0, gc0 = 0, gc1 = 0, gc2 = 0, gc3 = 0;
  float mym = 0.0f;

  if (tid < 64) {
    mi = idx[t16];      mt = thr[t16];      mlo = lastocc[t16];
    ni = idx[16 + t16]; nt = thr[16 + t16]; nlo = lastocc[16 + t16];
    grow = idx[16 + gt];
    gc0 = idx[16 + gq]; gc1 = idx[16 + gq + 1];
    gc2 = idx[16 + gq + 2]; gc3 = idx[16 + gq + 3];
    // synchronous S gather for chunk 0 (column-major, padded stride)
    int r0 = idx[gt];
    int c0 = idx[gq], c1 = idx[gq + 1], c2 = idx[gq + 2], c3 = idx[gq + 3];
    const float* Jr = J + (size_t)r0 * N;
    ST_lds[(gq + 0) * SST + gt] = Jr[c0];
    ST_lds[(gq + 1) * SST + gt] = Jr[c1];
    ST_lds[(gq + 2) * SST + gt] = Jr[c2];
    ST_lds[(gq + 3) * SST + gt] = Jr[c3];
  }
  __syncthreads();
  if (tid < 64) mym = m_lds[mi];

  for (int c = 0; c < NCHUNK; ++c) {
    // ---------------- P1: wave 0 resolves the 16 decisions ----------------
    if (tid < 64) {
      // issue S gather for c+1 (addresses already in regs; waited at store below)
      const float* Jg = J + (size_t)grow * N;
      float g0 = Jg[gc0], g1 = Jg[gc1], g2 = Jg[gc2], g3 = Jg[gc3];
      // issue idx/thr/lastocc/gather-addr loads for c+2
      int b2 = c * CHUNK + 32;
      if (b2 >= STEPS) b2 = 0;   // clamp: values unused on final chunks
      int n2i = idx[b2 + t16];
      double n2t = thr[b2 + t16];
      int n2lo = lastocc[b2 + t16];
      int g2row = idx[b2 + gt];
      int g2c0 = idx[b2 + gq];     int g2c1 = idx[b2 + gq + 1];
      int g2c2 = idx[b2 + gq + 2]; int g2c3 = idx[b2 + gq + 3];
      // this chunk's coupling column, register-resident:
      // Scol[j] = ST[t16*SST + j] = J[idx[j]][idx[t16]]
      const float* sp = &ST_lds[t16 * SST];
      float4 sa = *(const float4*)(sp + 0);
      float4 sb = *(const float4*)(sp + 4);
      float4 sc = *(const float4*)(sp + 8);
      float4 sd = *(const float4*)(sp + 12);
      double Ival = field_lds[mi];
      float mcur = mym;
      float finals = 0.0f, finald = 0.0f;
      int conf = -1;
      bool locked = false;
      // flip-driven resolve: rounds = flips + 1, no LDS on the chain
      while (true) {
        float s = (Ival >= mt) ? 1.0f : -1.0f;   // I >= atanh(r) <=> tanh(I) >= r
        float dl = s - mcur;
        unsigned long long mask = __ballot(dl != 0.0f) & 0xFFFFull;
        mask &= (~0ull) << (conf + 1);
        if (mask == 0) {
          if (!locked) { finals = s; finald = 0.0f; }
          break;
        }
        int f = (int)__builtin_ctzll(mask);      // wave-uniform
        if (!locked && t16 <= f) { finals = s; finald = dl; locked = true; }
        float dl_f = __int_as_float(__builtin_amdgcn_readlane(__float_as_int(dl), f));
        float s_f  = __int_as_float(__builtin_amdgcn_readlane(__float_as_int(s), f));
        int   i_f  = __builtin_amdgcn_readlane(mi, f);
        float xcol;                               // Scol[f], f uniform -> scalar branches
        switch (f) {
          case 0:  xcol = sa.x; break;  case 1:  xcol = sa.y; break;
          case 2:  xcol = sa.z; break;  case 3:  xcol = sa.w; break;
          case 4:  xcol = sb.x; break;  case 5:  xcol = sb.y; break;
          case 6:  xcol = sb.z; break;  case 7:  xcol = sb.w; break;
          case 8:  xcol = sc.x; break;  case 9:  xcol = sc.y; break;
          case 10: xcol = sc.z; break;  case 11: xcol = sc.w; break;
          case 12: xcol = sd.x; break;  case 13: xcol = sd.y; break;
          default: xcol = (f == 14) ? sd.z : sd.w; break;
        }
        Ival += (double)(xcol * dl_f);            // exact product: dl in {-2,2}
        if (mi == i_f) mcur = s_f;                // in-chunk duplicate index
        conf = f;
      }
      // publish: compacted flip list + m updates (last occurrence wins)
      unsigned long long fm = __ballot((tid < 16) && (finald != 0.0f));
      if (tid < 16) {
        if (finald != 0.0f) {
          int pos = __popcll(fm & ((1ull << t16) - 1ull));
          pubi_lds[pos] = mi;
          pubd_lds[pos] = finald;
        }
        if (mlo) m_lds[mi] = finals;
        if (tid == 0) pubF_lds = __popcll(fm);
      }
      // store S for chunk c+1 (waits the gather issued above ~resolve-length later)
      ST_lds[(gq + 0) * SST + gt] = g0;
      ST_lds[(gq + 1) * SST + gt] = g1;
      ST_lds[(gq + 2) * SST + gt] = g2;
      ST_lds[(gq + 3) * SST + gt] = g3;
      // m gather for next chunk (after this chunk's m writes; same wave, in-order)
      mym = m_lds[ni];
      // rotate pipeline registers
      mi = ni; mt = nt; mlo = nlo;
      ni = n2i; nt = n2t; nlo = n2lo;
      grow = g2row; gc0 = g2c0; gc1 = g2c1; gc2 = g2c2; gc3 = g2c3;
    }
    lgkm_barrier();

    // ---------------- P2: all threads apply the F flipped rows ----------------
    {
      int F = pubF_lds;
      if (F > 0) {                         // uniform: skip flip-free chunks
        int4 ra = *(const int4*)(pubi_lds + 0);
        int4 rb = *(const int4*)(pubi_lds + 4);
        int4 rc = *(const int4*)(pubi_lds + 8);
        int4 rd = *(const int4*)(pubi_lds + 12);
        float4 da = *(const float4*)(pubd_lds + 0);
        float4 db = *(const float4*)(pubd_lds + 4);
        float4 dc = *(const float4*)(pubd_lds + 8);
        float4 dd = *(const float4*)(pubd_lds + 12);
        int rows[CHUNK] = {ra.x, ra.y, ra.z, ra.w, rb.x, rb.y, rb.z, rb.w,
                           rc.x, rc.y, rc.z, rc.w, rd.x, rd.y, rd.z, rd.w};
        float dv[CHUNK] = {da.x, da.y, da.z, da.w, db.x, db.y, db.z, db.w,
                           dc.x, dc.y, dc.z, dc.w, dd.x, dd.y, dd.z, dd.w};
        const float* Jb = J + 4 * tid;
        float4 rv[CHUNK];
        // loads first (back-to-back issue, one latency exposure), guarded by
        // wave-uniform t<F branches; entries >= F never touched
#pragma unroll
        for (int t = 0; t < CHUNK; ++t)
          if (t < F) rv[t] = *(const float4*)(Jb + (size_t)rows[t] * N);
        float a0 = 0.f, a1 = 0.f, a2 = 0.f, a3 = 0.f;
#pragma unroll
        for (int t = 0; t < CHUNK; ++t)
          if (t < F) {
            a0 += rv[t].x * dv[t]; a1 += rv[t].y * dv[t];
            a2 += rv[t].z * dv[t]; a3 += rv[t].w * dv[t];
          }
        // chunk-local exact fp32 partials -> fp64 master, write-through to LDS
        i0 += (double)a0; i1 += (double)a1; i2 += (double)a2; i3 += (double)a3;
        *(double2*)(field_lds + 4 * tid + 0) = make_double2(i0, i1);
        *(double2*)(field_lds + 4 * tid + 2) = make_double2(i2, i3);
      }
    }
    lgkm_barrier();
  }

  __syncthreads();
  ((float4*)out)[tid] = ((const float4*)m_lds)[tid];
}

extern "C" void kernel_launch(void* const* d_in, const int* in_sizes, int n_in,
                              void* d_out, int out_size, void* d_ws, size_t ws_size,
                              hipStream_t stream) {
  const float* J = (const float*)d_in[0];
  const float* h = (const float*)d_in[1];
  const float* m0 = (const float*)d_in[2];
  const int* idx = (const int*)d_in[3];
  const float* u = (const float*)d_in[4];
  float* out = (float*)d_out;

  double* thr = (double*)d_ws;                                        // 16384 f64
  double* I0 = (double*)((char*)d_ws + STEPS * sizeof(double));       // 4096 f64
  int* lastocc = (int*)((char*)d_ws + STEPS * sizeof(double)
                                    + N * sizeof(double));            // 16384 i32

  pre_kernel<<<dim3(STEPS / 256), dim3(256), 0, stream>>>(u, idx, thr, lastocc);
  init_field_kernel<<<dim3(N), dim3(256), 0, stream>>>(J, h, m0, I0);
  pbit_kernel<<<dim3(1), dim3(MBLK), 0, stream>>>(J, m0, idx, thr, lastocc, I0, out);
}